// Round 8
// baseline (6244.731 us; speedup 1.0000x reference)
//
#include <hip/hip_runtime.h>

// Problem constants
#define Bn 4
#define Ln 256
#define Dn 256
#define Wn 8
#define NBLK 64          // persistent grid: 64 blocks (1 per CU subset, co-resident)
#define BLD (Bn*Ln*Dn)   // 262144
#define BDD (Bn*Dn*Dn)   // 262144

typedef float  floatx4 __attribute__((ext_vector_type(4)));
typedef short  short8  __attribute__((ext_vector_type(8)));

// -------------------------------------------------------------------------
// Coherent (cross-XCD) access helpers (sc0 sc1 -> bypass L1/L2, live at MALL)
// -------------------------------------------------------------------------
__device__ __forceinline__ float ldc(const float* p) {
    return __hip_atomic_load(p, __ATOMIC_RELAXED, __HIP_MEMORY_SCOPE_AGENT);
}
__device__ __forceinline__ void stc(float* p, float v) {
    __hip_atomic_store(p, v, __ATOMIC_RELAXED, __HIP_MEMORY_SCOPE_AGENT);
}
__device__ __forceinline__ void stc4(float* p, floatx4 v) {
    asm volatile("global_store_dwordx4 %0, %1, off sc0 sc1" :: "v"(p), "v"(v) : "memory");
}
__device__ __forceinline__ void ldc4x4(floatx4& a0, floatx4& a1, floatx4& a2, floatx4& a3,
    const float* p0, const float* p1, const float* p2, const float* p3)
{
    asm volatile(
        "global_load_dwordx4 %0, %4, off sc0 sc1\n\t"
        "global_load_dwordx4 %1, %5, off sc0 sc1\n\t"
        "global_load_dwordx4 %2, %6, off sc0 sc1\n\t"
        "global_load_dwordx4 %3, %7, off sc0 sc1\n\t"
        "s_waitcnt vmcnt(0)"
        : "=&v"(a0), "=&v"(a1), "=&v"(a2), "=&v"(a3)
        : "v"(p0), "v"(p1), "v"(p2), "v"(p3)
        : "memory");
}
__device__ __forceinline__ void ldc4x8(
    floatx4& a0, floatx4& a1, floatx4& a2, floatx4& a3,
    floatx4& b0, floatx4& b1, floatx4& b2, floatx4& b3,
    const float* p0, const float* p1, const float* p2, const float* p3,
    const float* q0, const float* q1, const float* q2, const float* q3)
{
    asm volatile(
        "global_load_dwordx4 %0, %8, off sc0 sc1\n\t"
        "global_load_dwordx4 %1, %9, off sc0 sc1\n\t"
        "global_load_dwordx4 %2, %10, off sc0 sc1\n\t"
        "global_load_dwordx4 %3, %11, off sc0 sc1\n\t"
        "global_load_dwordx4 %4, %12, off sc0 sc1\n\t"
        "global_load_dwordx4 %5, %13, off sc0 sc1\n\t"
        "global_load_dwordx4 %6, %14, off sc0 sc1\n\t"
        "global_load_dwordx4 %7, %15, off sc0 sc1\n\t"
        "s_waitcnt vmcnt(0)"
        : "=&v"(a0), "=&v"(a1), "=&v"(a2), "=&v"(a3),
          "=&v"(b0), "=&v"(b1), "=&v"(b2), "=&v"(b3)
        : "v"(p0), "v"(p1), "v"(p2), "v"(p3),
          "v"(q0), "v"(q1), "v"(q2), "v"(q3)
        : "memory");
}

// bf16 pack (RNE)
__device__ __forceinline__ unsigned f2bf(float x) {
    unsigned u = __float_as_uint(x);
    return (u + 0x7FFFu + ((u >> 16) & 1u)) >> 16;
}
__device__ __forceinline__ unsigned long long packbf4(floatx4 v) {
    unsigned lo = f2bf(v[0]) | (f2bf(v[1]) << 16);
    unsigned hi = f2bf(v[2]) | (f2bf(v[3]) << 16);
    return (unsigned long long)lo | ((unsigned long long)hi << 32);
}
union BF8 { short8 s8; unsigned long long u[2]; };

// -------------------------------------------------------------------------
// fence-free grid barrier (64 blocks), verified round 5/6
// -------------------------------------------------------------------------
__device__ __forceinline__ void grid_sync(unsigned* flags, unsigned k)
{
    asm volatile("s_waitcnt vmcnt(0) lgkmcnt(0)" ::: "memory");
    __syncthreads();
    if (threadIdx.x == 0)
        __hip_atomic_store(&flags[(unsigned)blockIdx.x * 32u], k,
                           __ATOMIC_RELAXED, __HIP_MEMORY_SCOPE_AGENT);
    if (threadIdx.x < NBLK) {
        while (__hip_atomic_load(&flags[(unsigned)threadIdx.x * 32u],
                                 __ATOMIC_RELAXED, __HIP_MEMORY_SCOPE_AGENT) < k)
            __builtin_amdgcn_s_sleep(1);
    }
    __syncthreads();
}

// -------------------------------------------------------------------------
// kphi + gamma    [verified round 2]
// -------------------------------------------------------------------------
__global__ __launch_bounds__(256) void kphi_gamma_kernel(
    const float* __restrict__ k_al, const float* __restrict__ x,
    const float* __restrict__ poly, const float* __restrict__ gW,
    const float* __restrict__ gb, float* __restrict__ kphi,
    float* __restrict__ gamma)
{
    int wg = blockIdx.x, tid = threadIdx.x;
    int wave = tid >> 6, lane = tid & 63;
    int n = wg * 4 + wave;
    float gacc = 0.f;
#pragma unroll
    for (int c = 0; c < 4; ++c) {
        int e = lane + 64 * c;
        float kv = k_al[n * Dn + e];
        kphi[n * Dn + e] = poly[e] * kv + poly[Dn + e] * kv * kv;
        gacc += x[n * Dn + e] * gW[e];
    }
#pragma unroll
    for (int off = 32; off; off >>= 1) gacc += __shfl_xor(gacc, off);
    if (lane == 0) gamma[n] = 1.f / (1.f + expf(-(gacc + gb[0])));
}

// -------------------------------------------------------------------------
// tiled GEMM  [verified round 2]
// -------------------------------------------------------------------------
template <int ACT>
__global__ __launch_bounds__(256) void gemm_act_kernel(
    const float* __restrict__ In, const float* __restrict__ Wm,
    const float* __restrict__ bias, float* __restrict__ Out)
{
    __shared__ float ldsX[32 * 64];
    __shared__ float ldsW[64 * 65];
    int n0 = blockIdx.x * 32;
    int m0 = blockIdx.y * 64;
    int tid = threadIdx.x;
    float acc[8] = {0, 0, 0, 0, 0, 0, 0, 0};
    for (int j0 = 0; j0 < 256; j0 += 64) {
#pragma unroll
        for (int q = 0; q < 2; ++q) {
            int fi = tid + 256 * q; int row = fi >> 4; int c4 = (fi & 15) << 2;
            *(float4*)&ldsX[row * 64 + c4] =
                *(const float4*)&In[(n0 + row) * 256 + j0 + c4];
        }
#pragma unroll
        for (int q = 0; q < 4; ++q) {
            int fi = tid + 256 * q; int row = fi >> 4; int c4 = (fi & 15) << 2;
            float4 vv = *(const float4*)&Wm[(m0 + row) * 256 + j0 + c4];
            ldsW[(c4 + 0) * 65 + row] = vv.x;
            ldsW[(c4 + 1) * 65 + row] = vv.y;
            ldsW[(c4 + 2) * 65 + row] = vv.z;
            ldsW[(c4 + 3) * 65 + row] = vv.w;
        }
        __syncthreads();
        int m = tid & 63, ng = tid >> 6;
        for (int j = 0; j < 64; ++j) {
            float wv = ldsW[j * 65 + m];
#pragma unroll
            for (int r = 0; r < 8; ++r) acc[r] += ldsX[(ng * 8 + r) * 64 + j] * wv;
        }
        __syncthreads();
    }
    int m = tid & 63, ng = tid >> 6;
    float bv = bias[m0 + m];
#pragma unroll
    for (int r = 0; r < 8; ++r) {
        float vv = acc[r] + bv;
        if (ACT == 1) vv = 1.f / (1.f + expf(-vv));
        if (ACT == 2) vv = 0.1f / (1.f + expf(-vv));
        Out[(n0 + ng * 8 + r) * 256 + m0 + m] = vv;
    }
}

// -------------------------------------------------------------------------
// K-gram precompute: Kall[b][t][wa*8+wb] = kphi_{t-7+wa} . kphi_{t-7+wb}
// -------------------------------------------------------------------------
__global__ __launch_bounds__(64) void kgram_kernel(
    const float* __restrict__ kphi, float* __restrict__ Kall)
{
    int t = blockIdx.x, b = blockIdx.y, tid = threadIdx.x;
    int wa = tid >> 3, wb = tid & 7;
    int ta = t - 7 + wa, tb = t - 7 + wb;
    float g = 0.f;
    if (ta >= 0 && tb >= 0) {
        const float* pa = &kphi[(b * Ln + ta) * Dn];
        const float* pb = &kphi[(b * Ln + tb) * Dn];
        for (int j = 0; j < Dn; j += 4) {
            floatx4 x1 = *(const floatx4*)&pa[j];
            floatx4 x2 = *(const floatx4*)&pb[j];
            g += x1[0]*x2[0] + x1[1]*x2[1] + x1[2]*x2[2] + x1[3]*x2[3];
        }
    }
    Kall[(b * Ln + t) * 64 + tid] = g;
}

// -------------------------------------------------------------------------
// prologue: zero ys, errp(2 slots), normbuf, flags (every launch)
// -------------------------------------------------------------------------
__global__ __launch_bounds__(256) void prologue_kernel(
    float* __restrict__ ys, float* __restrict__ errp,
    float* __restrict__ normbuf, unsigned* __restrict__ flags)
{
    int gidx = blockIdx.x * 256 + threadIdx.x;
    float4 z = {0.f, 0.f, 0.f, 0.f};
    ((float4*)ys)[gidx] = z;                          // 262144 floats
    if (gidx < 4096) ((float4*)errp)[gidx] = z;       // 16384 floats
    if (gidx < 256)  ((float4*)normbuf)[gidx] = z;    // 1024 floats
    if (gidx < 512)  {
        uint4 zu = {0u,0u,0u,0u};
        ((uint4*)flags)[gidx] = zu;                   // 2048 u32
    }
}

// -------------------------------------------------------------------------
// Persistent scan: 64 blocks x 256 threads. Block = (b, rem):
//   A-role: strip d0=rem*16 -> S strip in REGISTERS; q dots local; S update;
//           norm atomic; writes bf16 S^T panel + u/a vectors.
//   C-role: tile (i0,l0) -> M tile in REGISTERS, T panel (i0 x 256) in LDS
//           fp32 (incremental update); MFMA T*S; NS; M update; y partial;
//           next-step M.k partials (atomic) so A never needs M.
// 2 grid barriers per step; cross-block traffic ~ST panel (32KB) + vectors.
// -------------------------------------------------------------------------
#define OFF_T      0        // T_lds fp32 [64][260]            16640 floats
#define OFF_ST     16640    // ST_lds bf16 [64][264] (8448 fl) / A: Sstrip fp32 [16][260]
#define OFF_UV     25088    // uv [8][256]  (A: us [8][16] at same base)
#define OFF_AV     27136    // av [8][256]
#define OFF_CV     29184    // cv [8][256]
#define OFF_TH     31232    // thv [256]
#define OFF_KT     31488    // kT [256]
#define OFF_KW2    31744    // kW2 [8][256]
#define OFF_KWA    33792    // kW_A [8][260]
#define OFF_KL     35872    // Kl [64]
#define OFF_SRED   35936    // sred [64]

__global__ void __launch_bounds__(256, 1) scan_kernel(
    const float* __restrict__ kphi, const float* __restrict__ vin,
    const float* __restrict__ gammaB, const float* __restrict__ alphaB,
    const float* __restrict__ etaB, const float* __restrict__ thetaB,
    const float* __restrict__ Kall,
    const float* __restrict__ Mprev, const float* __restrict__ Sprev,
    unsigned short* __restrict__ STg,
    float* __restrict__ u_buf, float* __restrict__ a_buf,
    float* __restrict__ errp_g, float* __restrict__ normbuf,
    float* __restrict__ ysg, unsigned* __restrict__ flags,
    float* __restrict__ outM, float* __restrict__ outS)
{
    __shared__ float smem[36000];        // 144 KB
    float* T_lds = smem + OFF_T;
    float* uv    = smem + OFF_UV;
    float* av    = smem + OFF_AV;
    float* cv    = smem + OFF_CV;
    float* thv   = smem + OFF_TH;
    float* kT    = smem + OFF_KT;
    float* kW2   = smem + OFF_KW2;
    float* kWA   = smem + OFF_KWA;
    float* Kl    = smem + OFF_KL;
    float* sred  = smem + OFF_SRED;

    const int wg = blockIdx.x, tid = threadIdx.x;
    const int b   = wg >> 4;
    const int rem = wg & 15;
    const int i0 = (rem >> 2) * 64, l0 = (rem & 3) * 64;  // C tile
    const int d0 = rem << 4;                              // A strip
    const int wid = tid >> 6, lane = tid & 63;
    const int lme = lane & 15, hi = lane >> 4;
    const int ibr = i0 + wid * 16 + (hi << 2);            // C output rows (4: +g)
    const int r  = tid >> 4, m = tid & 15;                // A strip row / col group
    const int e0 = m * 16;
    unsigned kbar = 0;

    floatx4 S_reg[4];      // A: S[d0+r][e0..e0+16)
    float   M_reg[16];     // C: M[ibr+g][l0+lt*16+lme]

    // =========================== INIT ===========================
    {
#pragma unroll
        for (int cq = 0; cq < 4; ++cq)
            S_reg[cq] = *(const floatx4*)&Sprev[(size_t)(b*256 + d0 + r)*256 + e0 + cq*4];
#pragma unroll
        for (int lt = 0; lt < 4; ++lt)
#pragma unroll
            for (int g = 0; g < 4; ++g)
                M_reg[lt*4+g] = Mprev[(size_t)(b*256 + ibr + g)*256 + l0 + lt*16 + lme];

        // T panel = S_prev S_prev^T rows [i0, i0+64) x all k  (bf16 MFMA)
        for (int g4 = 0; g4 < 4; ++g4) {
            floatx4 acc[4];
#pragma unroll
            for (int lt = 0; lt < 4; ++lt) acc[lt] = (floatx4){0.f,0.f,0.f,0.f};
#pragma unroll
            for (int kc = 0; kc < 8; ++kc) {
                int kb2 = kc*32 + hi*8;
                floatx4 a0 = *(const floatx4*)&Sprev[(size_t)(b*256 + i0 + wid*16 + lme)*256 + kb2];
                floatx4 a1 = *(const floatx4*)&Sprev[(size_t)(b*256 + i0 + wid*16 + lme)*256 + kb2 + 4];
                BF8 ua; ua.u[0] = packbf4(a0); ua.u[1] = packbf4(a1);
#pragma unroll
                for (int lt = 0; lt < 4; ++lt) {
                    int brow = g4*64 + lt*16 + lme;
                    floatx4 b0 = *(const floatx4*)&Sprev[(size_t)(b*256 + brow)*256 + kb2];
                    floatx4 b1 = *(const floatx4*)&Sprev[(size_t)(b*256 + brow)*256 + kb2 + 4];
                    BF8 ub; ub.u[0] = packbf4(b0); ub.u[1] = packbf4(b1);
                    acc[lt] = __builtin_amdgcn_mfma_f32_16x16x32_bf16(ua.s8, ub.s8, acc[lt], 0,0,0);
                }
            }
#pragma unroll
            for (int lt = 0; lt < 4; ++lt)
#pragma unroll
                for (int g = 0; g < 4; ++g)
                    T_lds[(wid*16 + (hi<<2) + g)*260 + g4*64 + lt*16 + lme] = acc[lt][g];
        }

        // err partials for t=0 (window has only w=7 = token 0), slot 0
#pragma unroll
        for (int q = 0; q < 2; ++q) {
            int w = q*4 + (tid >> 6);
            int c4 = (tid & 63) << 2;
            floatx4 kv = {0.f,0.f,0.f,0.f};
            if (w == 7) kv = *(const floatx4*)&kphi[(size_t)(b*Ln)*Dn + c4];
            *(floatx4*)&kW2[w*256 + c4] = kv;
        }
        __syncthreads();
#pragma unroll
        for (int w = 0; w < 8; ++w) {
            float pd[4] = {0.f,0.f,0.f,0.f};
#pragma unroll
            for (int lt = 0; lt < 4; ++lt) {
                float kv2 = kW2[w*256 + l0 + lt*16 + lme];
#pragma unroll
                for (int g = 0; g < 4; ++g) pd[g] += M_reg[lt*4+g] * kv2;
            }
#pragma unroll
            for (int g = 0; g < 4; ++g) {
                pd[g] += __shfl_xor(pd[g], 1); pd[g] += __shfl_xor(pd[g], 2);
                pd[g] += __shfl_xor(pd[g], 4); pd[g] += __shfl_xor(pd[g], 8);
            }
            if (lme == 0)
#pragma unroll
                for (int g = 0; g < 4; ++g)
                    atomicAdd(&errp_g[(size_t)(0*4 + b)*2048 + w*256 + ibr + g], pd[g]);
        }
    }
    grid_sync(flags, ++kbar);

    for (int t = 0; t < Ln; ++t) {
        const int cwin = (t + 1 < Wn) ? (t + 1) : Wn;
        const float invc = 1.f / (float)cwin;

        // ======================= PHASE A =======================
        {
            // a1: stage kphi window
#pragma unroll
            for (int q = 0; q < 2; ++q) {
                int w = q*4 + (tid >> 6);
                int c4 = (tid & 63) << 2;
                int tk = t - 7 + w;
                floatx4 kv = {0.f,0.f,0.f,0.f};
                if (tk >= 0) kv = *(const floatx4*)&kphi[(size_t)(b*Ln + tk)*Dn + c4];
                *(floatx4*)&kWA[w*260 + c4] = kv;
            }
            __syncthreads();

            // a2a: q dots from register strip; a = theta*q
            {
                float qw[8] = {0,0,0,0,0,0,0,0};
#pragma unroll
                for (int cq = 0; cq < 4; ++cq) {
                    floatx4 sv = S_reg[cq];
#pragma unroll
                    for (int w = 0; w < 8; ++w) {
                        floatx4 kv = *(const floatx4*)&kWA[w*260 + e0 + cq*4];
                        qw[w] += sv[0]*kv[0] + sv[1]*kv[1] + sv[2]*kv[2] + sv[3]*kv[3];
                    }
                }
#pragma unroll
                for (int w = 0; w < 8; ++w) {
                    qw[w] += __shfl_xor(qw[w], 1); qw[w] += __shfl_xor(qw[w], 2);
                    qw[w] += __shfl_xor(qw[w], 4); qw[w] += __shfl_xor(qw[w], 8);
                }
                if (m < 8) {
                    float th = thetaB[(size_t)(b*Ln + t)*Dn + d0 + r];
                    stc(&a_buf[(size_t)(b*8 + m)*256 + d0 + r], th * qw[m]);
                }
            }
            // a2b: u from err partials (written by C at t-1); zero slot for reuse
            if (tid < 128) {
                int w = tid >> 4, rr = tid & 15;
                float* epp = &errp_g[(size_t)((t&1)*4 + b)*2048 + w*256 + d0 + rr];
                float ep = ldc(epp);
                stc(epp, 0.f);
                int tok = t - 7 + w;
                float uu = 0.f;
                if (tok >= 0)
                    uu = gammaB[b*Ln + tok] * invc *
                         (ep - vin[(size_t)(b*Ln + tok)*Dn + d0 + rr]);
                uv[w*16 + rr] = uu;     // local "us"
                stc(&u_buf[(size_t)(b*8 + w)*256 + d0 + rr], uu);
            }
            __syncthreads();

            // a4: S strip update + norm partial
            {
                float th = thetaB[(size_t)(b*Ln + t)*Dn + d0 + r];
                float uu[8];
#pragma unroll
                for (int w = 0; w < 8; ++w) uu[w] = uv[w*16 + r];
                float sumsq = 0.f;
#pragma unroll
                for (int cq = 0; cq < 4; ++cq) {
                    floatx4 sv = th * S_reg[cq];
#pragma unroll
                    for (int w = 0; w < 8; ++w) {
                        floatx4 kv = *(const floatx4*)&kWA[w*260 + e0 + cq*4];
                        sv += uu[w] * kv;
                    }
                    S_reg[cq] = sv;
                    sumsq += sv[0]*sv[0] + sv[1]*sv[1] + sv[2]*sv[2] + sv[3]*sv[3];
                }
#pragma unroll
                for (int off = 32; off; off >>= 1) sumsq += __shfl_xor(sumsq, off);
                if ((tid & 63) == 0) atomicAdd(&normbuf[t*4 + b], sumsq);
            }

            // a5: export S^T bf16 via LDS transpose
            {
                float* Sl = smem + OFF_ST;   // fp32 [16][260]
#pragma unroll
                for (int cq = 0; cq < 4; ++cq)
                    *(floatx4*)&Sl[r*260 + e0 + cq*4] = S_reg[cq];
                __syncthreads();
                int l = tid;
                unsigned dw[8];
#pragma unroll
                for (int j = 0; j < 8; ++j)
                    dw[j] = f2bf(Sl[(2*j)*260 + l]) | (f2bf(Sl[(2*j+1)*260 + l]) << 16);
                floatx4 p0 = { __uint_as_float(dw[0]), __uint_as_float(dw[1]),
                               __uint_as_float(dw[2]), __uint_as_float(dw[3]) };
                floatx4 p1 = { __uint_as_float(dw[4]), __uint_as_float(dw[5]),
                               __uint_as_float(dw[6]), __uint_as_float(dw[7]) };
                char* dstp = (char*)STg + ((size_t)(b*256 + l)*256 + d0)*2;
                stc4((float*)dstp, p0);
                stc4((float*)(dstp + 16), p1);
            }
            if (t == Ln - 1) {
#pragma unroll
                for (int cq = 0; cq < 4; ++cq)
                    *(floatx4*)&outS[(size_t)(b*256 + d0 + r)*256 + e0 + cq*4] = S_reg[cq];
            }
        }
        grid_sync(flags, ++kbar);

        // ======================= PHASE C =======================
        {
            // c1: batched staging
            {
                int lq = tid >> 2, kq = (tid & 3) * 64;
                const char* src = (const char*)STg + ((size_t)(b*256 + l0 + lq)*256 + kq)*2;
                floatx4 r0,r1,r2,r3,r4,r5,r6,r7;
                ldc4x8(r0,r1,r2,r3,r4,r5,r6,r7,
                       (const float*)(src+0),  (const float*)(src+16),
                       (const float*)(src+32), (const float*)(src+48),
                       (const float*)(src+64), (const float*)(src+80),
                       (const float*)(src+96), (const float*)(src+112));
                char* dst = (char*)(smem + OFF_ST) + (lq*264 + kq)*2;
                *(floatx4*)(dst+0)  = r0; *(floatx4*)(dst+16) = r1;
                *(floatx4*)(dst+32) = r2; *(floatx4*)(dst+48) = r3;
                *(floatx4*)(dst+64) = r4; *(floatx4*)(dst+80) = r5;
                *(floatx4*)(dst+96) = r6; *(floatx4*)(dst+112)= r7;

                floatx4 u0,u1,a0,a1;
                ldc4x4(u0,u1,a0,a1,
                       &u_buf[(size_t)b*2048 + tid*8], &u_buf[(size_t)b*2048 + tid*8 + 4],
                       &a_buf[(size_t)b*2048 + tid*8], &a_buf[(size_t)b*2048 + tid*8 + 4]);
                *(floatx4*)&uv[tid*8]     = u0; *(floatx4*)&uv[tid*8 + 4] = u1;
                *(floatx4*)&av[tid*8]     = a0; *(floatx4*)&av[tid*8 + 4] = a1;

                if (tid < 64) {
                    *(floatx4*)&thv[tid*4] = *(const floatx4*)&thetaB[(size_t)(b*Ln + t)*Dn + tid*4];
                    *(floatx4*)&kT[tid*4]  = *(const floatx4*)&kphi[(size_t)(b*Ln + t)*Dn + tid*4];
                }
                if (tid < 16)
                    *(floatx4*)&Kl[tid*4] = *(const floatx4*)&Kall[(size_t)(b*Ln + t)*64 + tid*4];
                if (t < Ln - 1) {
#pragma unroll
                    for (int q = 0; q < 2; ++q) {
                        int w = q*4 + (tid >> 6);
                        int c4 = (tid & 63) << 2;
                        int tk = t + 1 - 7 + w;
                        floatx4 kv = {0.f,0.f,0.f,0.f};
                        if (tk >= 0) kv = *(const floatx4*)&kphi[(size_t)(b*Ln + tk)*Dn + c4];
                        *(floatx4*)&kW2[w*256 + c4] = kv;
                    }
                }
                if (tid == 0) sred[0] = ldc(&normbuf[t*4 + b]);
            }
            __syncthreads();

            // c2: c = a + 0.5 * G * u
#pragma unroll
            for (int q = 0; q < 8; ++q) {
                int idx = q*256 + tid;
                int w = idx >> 8, e = idx & 255;
                float s = av[idx];
#pragma unroll
                for (int w2 = 0; w2 < 8; ++w2)
                    s += 0.5f * Kl[w*8 + w2] * uv[w2*256 + e];
                cv[idx] = s;
            }
            __syncthreads();

            // c3: T panel update in LDS: T = thth*T + u c^T + c u^T
            {
                int ig = tid >> 4;            // 0..15
                int iloc0 = ig * 4;
                int kg = (tid & 15) * 16;
                floatx4 thi = *(const floatx4*)&thv[i0 + iloc0];
                floatx4 thk[4], Trow[4][4];
#pragma unroll
                for (int j = 0; j < 4; ++j) thk[j] = *(const floatx4*)&thv[kg + 4*j];
#pragma unroll
                for (int ii = 0; ii < 4; ++ii)
#pragma unroll
                    for (int j = 0; j < 4; ++j) {
                        Trow[ii][j] = *(const floatx4*)&T_lds[(iloc0+ii)*260 + kg + 4*j];
                        Trow[ii][j] = (thi[ii] * thk[j]) * Trow[ii][j];
                    }
#pragma unroll
                for (int w = 0; w < 8; ++w) {
                    floatx4 ui4 = *(const floatx4*)&uv[w*256 + i0 + iloc0];
                    floatx4 ci4 = *(const floatx4*)&cv[w*256 + i0 + iloc0];
                    floatx4 uk[4], ck[4];
#pragma unroll
                    for (int j = 0; j < 4; ++j) {
                        uk[j] = *(const floatx4*)&uv[w*256 + kg + 4*j];
                        ck[j] = *(const floatx4*)&cv[w*256 + kg + 4*j];
                    }
#pragma unroll
                    for (int ii = 0; ii < 4; ++ii)
#pragma unroll
                        for (int j = 0; j < 4; ++j)
                            Trow[ii][j] += ui4[ii]*ck[j] + ci4[ii]*uk[j];
                }
#pragma unroll
                for (int ii = 0; ii < 4; ++ii)
#pragma unroll
                    for (int j = 0; j < 4; ++j)
                        *(floatx4*)&T_lds[(iloc0+ii)*260 + kg + 4*j] = Trow[ii][j];
            }
            __syncthreads();

            // c5: MFMA TS tile (A = T fp32->bf16 from LDS, B = S^T bf16 LDS)
            floatx4 acc[4];
#pragma unroll
            for (int lt = 0; lt < 4; ++lt) acc[lt] = (floatx4){0.f,0.f,0.f,0.f};
#pragma unroll
            for (int kc = 0; kc < 8; ++kc) {
                int kb2 = kc*32 + hi*8;
                floatx4 a0 = *(const floatx4*)&T_lds[(wid*16 + lme)*260 + kb2];
                floatx4 a1 = *(const floatx4*)&T_lds[(wid*16 + lme)*260 + kb2 + 4];
                BF8 ua; ua.u[0] = packbf4(a0); ua.u[1] = packbf4(a1);
#pragma unroll
                for (int lt = 0; lt < 4; ++lt) {
                    short8 bf = *(const short8*)((const char*)(smem + OFF_ST)
                                  + ((lt*16 + lme)*264 + kb2)*2);
                    acc[lt] = __builtin_amdgcn_mfma_f32_16x16x32_bf16(ua.s8, bf, acc[lt], 0,0,0);
                }
            }

            // c6: NS, M update, y
            {
                float nsq = sred[0];
                float nrm = sqrtf(nsq) + 1e-7f;
                float inv_n = 1.f / nrm;
                float w1 = 1.5f * inv_n;
                float w3 = 0.5f * inv_n * inv_n * inv_n;
                float alv[4], etv[4], kvr[4];
#pragma unroll
                for (int g = 0; g < 4; ++g) {
                    alv[g] = alphaB[(size_t)(b*Ln + t)*Dn + ibr + g];
                    etv[g] = etaB[(size_t)(b*Ln + t)*Dn + ibr + g];
                }
#pragma unroll
                for (int lt = 0; lt < 4; ++lt) kvr[lt] = kT[l0 + lt*16 + lme];
                float py[4] = {0.f,0.f,0.f,0.f};
#pragma unroll
                for (int lt = 0; lt < 4; ++lt)
#pragma unroll
                    for (int g = 0; g < 4; ++g) {
                        int l_loc = lt*16 + lme;
                        unsigned short sb = *(const unsigned short*)
                            ((const char*)(smem + OFF_ST) + (l_loc*264 + ibr + g)*2);
                        float s_il = __uint_as_float(((unsigned)sb) << 16);
                        float ns = w1 * s_il - w3 * acc[lt][g];
                        float mn = alv[g] * M_reg[lt*4+g] - etv[g] * ns;
                        M_reg[lt*4+g] = mn;
                        py[g] += mn * kvr[lt];
                        if (t == Ln - 1)
                            outM[(size_t)(b*256 + ibr + g)*256 + l0 + l_loc] = mn;
                    }
#pragma unroll
                for (int g = 0; g < 4; ++g) {
                    py[g] += __shfl_xor(py[g], 1); py[g] += __shfl_xor(py[g], 2);
                    py[g] += __shfl_xor(py[g], 4); py[g] += __shfl_xor(py[g], 8);
                    if (lme == 0) atomicAdd(&ysg[(size_t)(b*Ln + t)*Dn + ibr + g], py[g]);
                }
            }

            // c7: next-step err partials (M_new . k_w), into slot (t+1)&1
            if (t < Ln - 1) {
#pragma unroll
                for (int w = 0; w < 8; ++w) {
                    float pd[4] = {0.f,0.f,0.f,0.f};
#pragma unroll
                    for (int lt = 0; lt < 4; ++lt) {
                        float kv2 = kW2[w*256 + l0 + lt*16 + lme];
#pragma unroll
                        for (int g = 0; g < 4; ++g) pd[g] += M_reg[lt*4+g] * kv2;
                    }
#pragma unroll
                    for (int g = 0; g < 4; ++g) {
                        pd[g] += __shfl_xor(pd[g], 1); pd[g] += __shfl_xor(pd[g], 2);
                        pd[g] += __shfl_xor(pd[g], 4); pd[g] += __shfl_xor(pd[g], 8);
                    }
                    if (lme == 0)
#pragma unroll
                        for (int g = 0; g < 4; ++g)
                            atomicAdd(&errp_g[(size_t)(((t+1)&1)*4 + b)*2048 + w*256 + ibr + g], pd[g]);
                }
            }
        }
        grid_sync(flags, ++kbar);
    }
}

// -------------------------------------------------------------------------
extern "C" void kernel_launch(void* const* d_in, const int* in_sizes, int n_in,
                              void* d_out, int out_size, void* d_ws, size_t ws_size,
                              hipStream_t stream)
{
    const float* x       = (const float*)d_in[0];
    const float* k_al    = (const float*)d_in[1];
    const float* v       = (const float*)d_in[2];
    const float* M_prev  = (const float*)d_in[3];
    const float* S_prev  = (const float*)d_in[4];
    const float* poly    = (const float*)d_in[5];
    const float* alpha_W = (const float*)d_in[6];
    const float* alpha_b = (const float*)d_in[7];
    const float* eta_W   = (const float*)d_in[8];
    const float* eta_b   = (const float*)d_in[9];
    const float* theta_W = (const float*)d_in[10];
    const float* theta_b = (const float*)d_in[11];
    const float* gamma_W = (const float*)d_in[12];
    const float* gamma_b = (const float*)d_in[13];
    const float* out_W   = (const float*)d_in[14];
    const float* out_b   = (const float*)d_in[15];

    float* ws = (float*)d_ws;
    float* kphi    = ws;                    // 262144
    float* alphaB  = kphi   + BLD;          // 262144
    float* etaB    = alphaB + BLD;          // 262144
    float* thetaB  = etaB   + BLD;          // 262144
    float* gammaB  = thetaB + BLD;          // 1024
    float* Kall    = gammaB + Bn*Ln;        // 65536
    float* STg_f   = Kall   + Bn*Ln*64;     // 131072 floats (bf16 [B][256][256] = 524288 B)
    float* u_bufp  = STg_f  + 131072;       // 8192   <-- ROUND-7 BUG: was +65536 (half the
    float* a_bufp  = u_bufp + Bn*Wn*Dn;     // 8192       ST size); b>=2 ST writes clobbered
    float* errp    = a_bufp + Bn*Wn*Dn;     // 16384      u/a/errp/normbuf -> sqrt(neg)=NaN
    float* normbuf = errp   + 16384;        // 1024
    float* ysws    = normbuf + Ln*Bn;       // 262144
    unsigned* flags = (unsigned*)(ysws + BLD);  // 2048 u32

    float* out_y = (float*)d_out;           // [B,L,D]
    float* outM  = out_y + BLD;             // [B,D,D]
    float* outS  = outM + BDD;              // [B,D,D]

    // precompute
    hipLaunchKernelGGL(kphi_gamma_kernel, dim3(256), dim3(256), 0, stream,
                       k_al, x, poly, gamma_W, gamma_b, kphi, gammaB);
    hipLaunchKernelGGL((gemm_act_kernel<1>), dim3(32, 4), dim3(256), 0, stream,
                       x, alpha_W, alpha_b, alphaB);
    hipLaunchKernelGGL((gemm_act_kernel<2>), dim3(32, 4), dim3(256), 0, stream,
                       x, eta_W, eta_b, etaB);
    hipLaunchKernelGGL((gemm_act_kernel<1>), dim3(32, 4), dim3(256), 0, stream,
                       x, theta_W, theta_b, thetaB);
    hipLaunchKernelGGL(kgram_kernel, dim3(Ln, Bn), dim3(64), 0, stream,
                       kphi, Kall);
    hipLaunchKernelGGL(prologue_kernel, dim3(256), dim3(256), 0, stream,
                       ysws, errp, normbuf, flags);

    // persistent scan
    hipLaunchKernelGGL(scan_kernel, dim3(NBLK), dim3(256), 0, stream,
                       kphi, v, gammaB, alphaB, etaB, thetaB, Kall,
                       M_prev, S_prev, (unsigned short*)STg_f,
                       u_bufp, a_bufp, errp, normbuf, ysws, flags,
                       outM, outS);

    // out projection
    hipLaunchKernelGGL((gemm_act_kernel<0>), dim3(32, 4), dim3(256), 0, stream,
                       ysws, out_W, out_b, out_y);
}

// Round 9
// 5753.373 us; speedup vs baseline: 1.0854x; 1.0854x over previous
//
#include <hip/hip_runtime.h>

// Problem constants
#define Bn 4
#define Ln 256
#define Dn 256
#define Wn 8
#define NBLK 64          // persistent grid: 16 blocks per batch
#define BLD (Bn*Ln*Dn)   // 262144
#define BDD (Bn*Dn*Dn)   // 262144

typedef float  floatx4 __attribute__((ext_vector_type(4)));
typedef short  short8  __attribute__((ext_vector_type(8)));

// -------------------------------------------------------------------------
// Coherent (cross-XCD) access helpers: sc0 sc1 -> bypass L1/L2, live at MALL
// -------------------------------------------------------------------------
__device__ __forceinline__ float ldc(const float* p) {
    return __hip_atomic_load(p, __ATOMIC_RELAXED, __HIP_MEMORY_SCOPE_AGENT);
}
__device__ __forceinline__ void stc(float* p, float v) {
    __hip_atomic_store(p, v, __ATOMIC_RELAXED, __HIP_MEMORY_SCOPE_AGENT);
}
__device__ __forceinline__ void stc4(float* p, floatx4 v) {
    asm volatile("global_store_dwordx4 %0, %1, off sc0 sc1" :: "v"(p), "v"(v) : "memory");
}
// 4 scalar loads, one waitcnt
__device__ __forceinline__ void ldc1x4(float& a, float& b, float& c, float& d,
    const float* p0, const float* p1, const float* p2, const float* p3)
{
    asm volatile(
        "global_load_dword %0, %4, off sc0 sc1\n\t"
        "global_load_dword %1, %5, off sc0 sc1\n\t"
        "global_load_dword %2, %6, off sc0 sc1\n\t"
        "global_load_dword %3, %7, off sc0 sc1\n\t"
        "s_waitcnt vmcnt(0)"
        : "=&v"(a), "=&v"(b), "=&v"(c), "=&v"(d)
        : "v"(p0), "v"(p1), "v"(p2), "v"(p3)
        : "memory");
}
// 12 x b128 + 1 scalar, single waitcnt (c1 mega-batch: one MALL round trip)
__device__ __forceinline__ void ldc4x12s(
    floatx4& r0, floatx4& r1, floatx4& r2, floatx4& r3,
    floatx4& r4, floatx4& r5, floatx4& r6, floatx4& r7,
    floatx4& r8, floatx4& r9, floatx4& r10, floatx4& r11, float& sc,
    const float* p0, const float* p1, const float* p2, const float* p3,
    const float* p4, const float* p5, const float* p6, const float* p7,
    const float* p8, const float* p9, const float* p10, const float* p11,
    const float* ps)
{
    asm volatile(
        "global_load_dwordx4 %0, %13, off sc0 sc1\n\t"
        "global_load_dwordx4 %1, %14, off sc0 sc1\n\t"
        "global_load_dwordx4 %2, %15, off sc0 sc1\n\t"
        "global_load_dwordx4 %3, %16, off sc0 sc1\n\t"
        "global_load_dwordx4 %4, %17, off sc0 sc1\n\t"
        "global_load_dwordx4 %5, %18, off sc0 sc1\n\t"
        "global_load_dwordx4 %6, %19, off sc0 sc1\n\t"
        "global_load_dwordx4 %7, %20, off sc0 sc1\n\t"
        "global_load_dwordx4 %8, %21, off sc0 sc1\n\t"
        "global_load_dwordx4 %9, %22, off sc0 sc1\n\t"
        "global_load_dwordx4 %10, %23, off sc0 sc1\n\t"
        "global_load_dwordx4 %11, %24, off sc0 sc1\n\t"
        "global_load_dword %12, %25, off sc0 sc1\n\t"
        "s_waitcnt vmcnt(0)"
        : "=&v"(r0), "=&v"(r1), "=&v"(r2), "=&v"(r3),
          "=&v"(r4), "=&v"(r5), "=&v"(r6), "=&v"(r7),
          "=&v"(r8), "=&v"(r9), "=&v"(r10), "=&v"(r11), "=&v"(sc)
        : "v"(p0), "v"(p1), "v"(p2), "v"(p3), "v"(p4), "v"(p5),
          "v"(p6), "v"(p7), "v"(p8), "v"(p9), "v"(p10), "v"(p11), "v"(ps)
        : "memory");
}

// bf16 pack (RNE)
__device__ __forceinline__ unsigned f2bf(float x) {
    unsigned u = __float_as_uint(x);
    return (u + 0x7FFFu + ((u >> 16) & 1u)) >> 16;
}
__device__ __forceinline__ unsigned long long packbf4(floatx4 v) {
    unsigned lo = f2bf(v[0]) | (f2bf(v[1]) << 16);
    unsigned hi = f2bf(v[2]) | (f2bf(v[3]) << 16);
    return (unsigned long long)lo | ((unsigned long long)hi << 32);
}
union BF8 { short8 s8; unsigned long long u[2]; };

// -------------------------------------------------------------------------
// fence-free PER-BATCH barrier (16 blocks): decouples the 4 batches
// -------------------------------------------------------------------------
__device__ __forceinline__ void grid_sync_b(unsigned* bflags, int rem, unsigned k)
{
    asm volatile("s_waitcnt vmcnt(0) lgkmcnt(0)" ::: "memory");
    __syncthreads();
    if (threadIdx.x == 0)
        __hip_atomic_store(&bflags[rem * 32], k,
                           __ATOMIC_RELAXED, __HIP_MEMORY_SCOPE_AGENT);
    if (threadIdx.x < 16) {
        while (__hip_atomic_load(&bflags[threadIdx.x * 32],
                                 __ATOMIC_RELAXED, __HIP_MEMORY_SCOPE_AGENT) < k)
            __builtin_amdgcn_s_sleep(1);
    }
    __syncthreads();
}

// -------------------------------------------------------------------------
// kphi + gamma    [verified round 2]
// -------------------------------------------------------------------------
__global__ __launch_bounds__(256) void kphi_gamma_kernel(
    const float* __restrict__ k_al, const float* __restrict__ x,
    const float* __restrict__ poly, const float* __restrict__ gW,
    const float* __restrict__ gb, float* __restrict__ kphi,
    float* __restrict__ gamma)
{
    int wg = blockIdx.x, tid = threadIdx.x;
    int wave = tid >> 6, lane = tid & 63;
    int n = wg * 4 + wave;
    float gacc = 0.f;
#pragma unroll
    for (int c = 0; c < 4; ++c) {
        int e = lane + 64 * c;
        float kv = k_al[n * Dn + e];
        kphi[n * Dn + e] = poly[e] * kv + poly[Dn + e] * kv * kv;
        gacc += x[n * Dn + e] * gW[e];
    }
#pragma unroll
    for (int off = 32; off; off >>= 1) gacc += __shfl_xor(gacc, off);
    if (lane == 0) gamma[n] = 1.f / (1.f + expf(-(gacc + gb[0])));
}

// -------------------------------------------------------------------------
// tiled GEMM  [verified round 2]
// -------------------------------------------------------------------------
template <int ACT>
__global__ __launch_bounds__(256) void gemm_act_kernel(
    const float* __restrict__ In, const float* __restrict__ Wm,
    const float* __restrict__ bias, float* __restrict__ Out)
{
    __shared__ float ldsX[32 * 64];
    __shared__ float ldsW[64 * 65];
    int n0 = blockIdx.x * 32;
    int m0 = blockIdx.y * 64;
    int tid = threadIdx.x;
    float acc[8] = {0, 0, 0, 0, 0, 0, 0, 0};
    for (int j0 = 0; j0 < 256; j0 += 64) {
#pragma unroll
        for (int q = 0; q < 2; ++q) {
            int fi = tid + 256 * q; int row = fi >> 4; int c4 = (fi & 15) << 2;
            *(float4*)&ldsX[row * 64 + c4] =
                *(const float4*)&In[(n0 + row) * 256 + j0 + c4];
        }
#pragma unroll
        for (int q = 0; q < 4; ++q) {
            int fi = tid + 256 * q; int row = fi >> 4; int c4 = (fi & 15) << 2;
            float4 vv = *(const float4*)&Wm[(m0 + row) * 256 + j0 + c4];
            ldsW[(c4 + 0) * 65 + row] = vv.x;
            ldsW[(c4 + 1) * 65 + row] = vv.y;
            ldsW[(c4 + 2) * 65 + row] = vv.z;
            ldsW[(c4 + 3) * 65 + row] = vv.w;
        }
        __syncthreads();
        int m = tid & 63, ng = tid >> 6;
        for (int j = 0; j < 64; ++j) {
            float wv = ldsW[j * 65 + m];
#pragma unroll
            for (int r = 0; r < 8; ++r) acc[r] += ldsX[(ng * 8 + r) * 64 + j] * wv;
        }
        __syncthreads();
    }
    int m = tid & 63, ng = tid >> 6;
    float bv = bias[m0 + m];
#pragma unroll
    for (int r = 0; r < 8; ++r) {
        float vv = acc[r] + bv;
        if (ACT == 1) vv = 1.f / (1.f + expf(-vv));
        if (ACT == 2) vv = 0.1f / (1.f + expf(-vv));
        Out[(n0 + ng * 8 + r) * 256 + m0 + m] = vv;
    }
}

// -------------------------------------------------------------------------
// K-gram precompute   [verified round 8]
// -------------------------------------------------------------------------
__global__ __launch_bounds__(64) void kgram_kernel(
    const float* __restrict__ kphi, float* __restrict__ Kall)
{
    int t = blockIdx.x, b = blockIdx.y, tid = threadIdx.x;
    int wa = tid >> 3, wb = tid & 7;
    int ta = t - 7 + wa, tb = t - 7 + wb;
    float g = 0.f;
    if (ta >= 0 && tb >= 0) {
        const float* pa = &kphi[(b * Ln + ta) * Dn];
        const float* pb = &kphi[(b * Ln + tb) * Dn];
        for (int j = 0; j < Dn; j += 4) {
            floatx4 x1 = *(const floatx4*)&pa[j];
            floatx4 x2 = *(const floatx4*)&pb[j];
            g += x1[0]*x2[0] + x1[1]*x2[1] + x1[2]*x2[2] + x1[3]*x2[3];
        }
    }
    Kall[(b * Ln + t) * 64 + tid] = g;
}

// -------------------------------------------------------------------------
// prologue: zero barrier flags (monotonic epochs need clean start each call)
// -------------------------------------------------------------------------
__global__ __launch_bounds__(256) void prologue_kernel(unsigned* __restrict__ flags)
{
    int gidx = blockIdx.x * 256 + threadIdx.x;
    if (gidx < 512) {
        uint4 zu = {0u, 0u, 0u, 0u};
        ((uint4*)flags)[gidx] = zu;   // 2048 u32
    }
}

// -------------------------------------------------------------------------
// ysum: fold 4 l0-slot partials of y into slot 0 (replaces ys atomics)
// -------------------------------------------------------------------------
__global__ __launch_bounds__(256) void ysum_kernel(float* __restrict__ ysp)
{
    int gidx = blockIdx.x * 256 + threadIdx.x;   // 65536 float4 units
    float4 a = ((float4*)ysp)[gidx];
    float4 b = ((float4*)ysp)[65536 + gidx];
    float4 c = ((float4*)ysp)[131072 + gidx];
    float4 d = ((float4*)ysp)[196608 + gidx];
    a.x += b.x + c.x + d.x;
    a.y += b.y + c.y + d.y;
    a.z += b.z + c.z + d.z;
    a.w += b.w + c.w + d.w;
    ((float4*)ysp)[gidx] = a;
}

// -------------------------------------------------------------------------
// Persistent scan. 64 blocks (16/batch) x 256 threads. Block = (b, rem):
//  A-role strip d0=rem*16: S fp32 in regs; C-role tile (i0,l0): M fp32 regs,
//  T fp32 in regs in MFMA-A-frag layout (no LDS T array -> no 16-way
//  conflicts). Zero MALL atomics: errp/ys/norm all slot-stored.
// -------------------------------------------------------------------------
#define OFF_ST    0        // bf16 [64][264] S^T panel (8448 fl); init scratch alias
#define OFF_UV    8448     // [8][256]
#define OFF_AV    10496    // [8][256]
#define OFF_CV    12544    // [8][256]
#define OFF_TH    14592    // [256]
#define OFF_KT    14848    // [256]
#define OFF_KL    15104    // [64]
#define OFF_NRM   15168    // [16]
#define OFF_WSUM  15184    // [4]
#define OFF_US    15200    // [8][16]
#define OFF_KWA   15328    // [8][260]
#define OFF_KW2   17408    // [8][256]
#define OFF_SL    19456    // [16][260]
#define SMEM_FLOATS 23616  // 94.5 KB

__global__ void __launch_bounds__(256, 1) scan_kernel(
    const float* __restrict__ kphi, const float* __restrict__ vin,
    const float* __restrict__ gammaB, const float* __restrict__ alphaB,
    const float* __restrict__ etaB, const float* __restrict__ thetaB,
    const float* __restrict__ Kall,
    const float* __restrict__ Mprev, const float* __restrict__ Sprev,
    unsigned short* __restrict__ STg,
    float* __restrict__ u_buf, float* __restrict__ a_buf,
    float* __restrict__ errp_g, float* __restrict__ normp,
    float* __restrict__ ysp, unsigned* __restrict__ flags,
    float* __restrict__ outM, float* __restrict__ outS)
{
    __shared__ float smem[SMEM_FLOATS];
    char*  STb  = (char*)(smem + OFF_ST);
    float* uvp  = smem + OFF_UV;
    float* avp  = smem + OFF_AV;
    float* cvp  = smem + OFF_CV;
    float* thv  = smem + OFF_TH;
    float* kT   = smem + OFF_KT;
    float* Kl   = smem + OFF_KL;
    float* nrml = smem + OFF_NRM;
    float* wsum = smem + OFF_WSUM;
    float* usl  = smem + OFF_US;
    float* kWA  = smem + OFF_KWA;
    float* kW2  = smem + OFF_KW2;
    float* Sl   = smem + OFF_SL;

    const int wg = blockIdx.x, tid = threadIdx.x;
    const int b   = wg >> 4;
    const int rem = wg & 15;
    const int s   = rem & 3;                               // l0-slot id
    const int i0 = (rem >> 2) * 64, l0 = (rem & 3) * 64;   // C tile
    const int d0 = rem << 4;                               // A strip
    const int wid = tid >> 6, lane = tid & 63;
    const int lme = lane & 15, hi = lane >> 4;
    const int ibr = i0 + wid * 16 + (hi << 2);             // C output rows
    const int r  = tid >> 4, m = tid & 15;                 // A row / col group
    unsigned* bflags = flags + b * 512;
    unsigned kbar = 0;

    floatx4 S_reg[4];    // A: S[d0+r][m*4+64*cq ..+4)
    float   M_reg[16];   // C: M[ibr+g][l0+lt*16+lme]
    floatx4 T_reg[16];   // C: T[16wid+lme][kc*32+hi*8 ..] A-frag layout, fp32

    // =========================== INIT ===========================
    {
#pragma unroll
        for (int cq = 0; cq < 4; ++cq)
            S_reg[cq] = *(const floatx4*)&Sprev[(size_t)(b*256 + d0 + r)*256 + m*4 + 64*cq];
#pragma unroll
        for (int lt = 0; lt < 4; ++lt)
#pragma unroll
            for (int g = 0; g < 4; ++g)
                M_reg[lt*4+g] = Mprev[(size_t)(b*256 + ibr + g)*256 + l0 + lt*16 + lme];

        // T panel = Sprev Sprev^T rows [i0,i0+64) x all k  (bf16 MFMA) -> scratch
        float* scratch = smem;   // [64][260] fp32, aliases ST..cv (init only)
        for (int g4 = 0; g4 < 4; ++g4) {
            floatx4 acc[4];
#pragma unroll
            for (int lt = 0; lt < 4; ++lt) acc[lt] = (floatx4){0.f,0.f,0.f,0.f};
#pragma unroll
            for (int kc = 0; kc < 8; ++kc) {
                int kb2 = kc*32 + hi*8;
                floatx4 a0 = *(const floatx4*)&Sprev[(size_t)(b*256 + i0 + wid*16 + lme)*256 + kb2];
                floatx4 a1 = *(const floatx4*)&Sprev[(size_t)(b*256 + i0 + wid*16 + lme)*256 + kb2 + 4];
                BF8 ua; ua.u[0] = packbf4(a0); ua.u[1] = packbf4(a1);
#pragma unroll
                for (int lt = 0; lt < 4; ++lt) {
                    int brow = g4*64 + lt*16 + lme;
                    floatx4 b0 = *(const floatx4*)&Sprev[(size_t)(b*256 + brow)*256 + kb2];
                    floatx4 b1 = *(const floatx4*)&Sprev[(size_t)(b*256 + brow)*256 + kb2 + 4];
                    BF8 ub; ub.u[0] = packbf4(b0); ub.u[1] = packbf4(b1);
                    acc[lt] = __builtin_amdgcn_mfma_f32_16x16x32_bf16(ua.s8, ub.s8, acc[lt], 0,0,0);
                }
            }
#pragma unroll
            for (int lt = 0; lt < 4; ++lt)
#pragma unroll
                for (int g = 0; g < 4; ++g)
                    scratch[(wid*16 + (hi<<2) + g)*260 + g4*64 + lt*16 + lme] = acc[lt][g];
        }
        __syncthreads();
        // read back in A-frag layout
#pragma unroll
        for (int kc = 0; kc < 8; ++kc) {
            T_reg[kc*2+0] = *(floatx4*)&scratch[(wid*16 + lme)*260 + kc*32 + hi*8];
            T_reg[kc*2+1] = *(floatx4*)&scratch[(wid*16 + lme)*260 + kc*32 + hi*8 + 4];
        }
        // t=0 err partials (window only has w=7 = token 0), parity 0, slot s
#pragma unroll
        for (int q = 0; q < 2; ++q) {
            int w = q*4 + (tid >> 6);
            int c4 = (tid & 63) << 2;
            floatx4 kv = {0.f,0.f,0.f,0.f};
            if (w == 7) kv = *(const floatx4*)&kphi[(size_t)(b*Ln)*Dn + c4];
            *(floatx4*)&kW2[w*256 + c4] = kv;
        }
        __syncthreads();
#pragma unroll
        for (int w = 0; w < 8; ++w) {
            float pd[4] = {0.f,0.f,0.f,0.f};
#pragma unroll
            for (int lt = 0; lt < 4; ++lt) {
                float kv2 = kW2[w*256 + l0 + lt*16 + lme];
#pragma unroll
                for (int g = 0; g < 4; ++g) pd[g] += M_reg[lt*4+g] * kv2;
            }
#pragma unroll
            for (int g = 0; g < 4; ++g) {
                pd[g] += __shfl_xor(pd[g], 1); pd[g] += __shfl_xor(pd[g], 2);
                pd[g] += __shfl_xor(pd[g], 4); pd[g] += __shfl_xor(pd[g], 8);
            }
            if (lme == 0)
#pragma unroll
                for (int g = 0; g < 4; ++g)
                    stc(&errp_g[(size_t)((s*2 + 0)*4 + b)*2048 + w*256 + ibr + g], pd[g]);
        }
    }
    grid_sync_b(bflags, rem, ++kbar);

    for (int t = 0; t < Ln; ++t) {
        const int cwin = (t + 1 < Wn) ? (t + 1) : Wn;
        const float invc = 1.f / (float)cwin;

        // ======================= PHASE A =======================
        {
            float e0_ = 0.f, e1_ = 0.f, e2_ = 0.f, e3_ = 0.f;
            int w_a = 0, rr_a = 0;
            const int p = t & 1;
            if (tid < 128) {
                // one batched RT: 4 errp slots
                w_a = tid >> 4; rr_a = tid & 15;
                ldc1x4(e0_, e1_, e2_, e3_,
                    &errp_g[(size_t)((0*2 + p)*4 + b)*2048 + w_a*256 + d0 + rr_a],
                    &errp_g[(size_t)((1*2 + p)*4 + b)*2048 + w_a*256 + d0 + rr_a],
                    &errp_g[(size_t)((2*2 + p)*4 + b)*2048 + w_a*256 + d0 + rr_a],
                    &errp_g[(size_t)((3*2 + p)*4 + b)*2048 + w_a*256 + d0 + rr_a]);
                float ep = e0_ + e1_ + e2_ + e3_;
                int tok = t - 7 + w_a;
                float uu = 0.f;
                if (tok >= 0)
                    uu = gammaB[b*Ln + tok] * invc *
                         (ep - vin[(size_t)(b*Ln + tok)*Dn + d0 + rr_a]);
                usl[w_a*16 + rr_a] = uu;
                stc(&u_buf[(size_t)(b*8 + w_a)*256 + d0 + rr_a], uu);
            } else {
                // concurrently: stage kphi window
                int idx = tid - 128;
                int w = idx >> 4, seg = idx & 15;
                int tk = t - 7 + w;
#pragma unroll
                for (int q = 0; q < 4; ++q) {
                    floatx4 kv = {0.f,0.f,0.f,0.f};
                    if (tk >= 0)
                        kv = *(const floatx4*)&kphi[(size_t)(b*Ln + tk)*Dn + seg*16 + q*4];
                    *(floatx4*)&kWA[w*260 + seg*16 + q*4] = kv;
                }
            }
            __syncthreads();

            // q dots (register strip) ; a = theta*q
            {
                float qw[8] = {0,0,0,0,0,0,0,0};
#pragma unroll
                for (int cq = 0; cq < 4; ++cq) {
                    floatx4 sv = S_reg[cq];
#pragma unroll
                    for (int w = 0; w < 8; ++w) {
                        floatx4 kv = *(const floatx4*)&kWA[w*260 + m*4 + 64*cq];
                        qw[w] += sv[0]*kv[0] + sv[1]*kv[1] + sv[2]*kv[2] + sv[3]*kv[3];
                    }
                }
#pragma unroll
                for (int w = 0; w < 8; ++w) {
                    qw[w] += __shfl_xor(qw[w], 1); qw[w] += __shfl_xor(qw[w], 2);
                    qw[w] += __shfl_xor(qw[w], 4); qw[w] += __shfl_xor(qw[w], 8);
                }
                if (m < 8) {
                    float th = thetaB[(size_t)(b*Ln + t)*Dn + d0 + r];
                    stc(&a_buf[(size_t)(b*8 + m)*256 + d0 + r], th * qw[m]);
                }
            }
            // S update + norm partial
            {
                float th = thetaB[(size_t)(b*Ln + t)*Dn + d0 + r];
                float uu[8];
#pragma unroll
                for (int w = 0; w < 8; ++w) uu[w] = usl[w*16 + r];
                float sumsq = 0.f;
#pragma unroll
                for (int cq = 0; cq < 4; ++cq) {
                    floatx4 sv = th * S_reg[cq];
#pragma unroll
                    for (int w = 0; w < 8; ++w) {
                        floatx4 kv = *(const floatx4*)&kWA[w*260 + m*4 + 64*cq];
                        sv += uu[w] * kv;
                    }
                    S_reg[cq] = sv;
                    sumsq += sv[0]*sv[0] + sv[1]*sv[1] + sv[2]*sv[2] + sv[3]*sv[3];
                }
#pragma unroll
                for (int off = 32; off; off >>= 1) sumsq += __shfl_xor(sumsq, off);
                if (lane == 0) wsum[wid] = sumsq;
            }
            // export S^T bf16 via LDS transpose; finish norm slot
            {
#pragma unroll
                for (int cq = 0; cq < 4; ++cq)
                    *(floatx4*)&Sl[r*260 + m*4 + 64*cq] = S_reg[cq];
                __syncthreads();
                int l = tid;
                unsigned dw[8];
#pragma unroll
                for (int j = 0; j < 8; ++j)
                    dw[j] = f2bf(Sl[(2*j)*260 + l]) | (f2bf(Sl[(2*j+1)*260 + l]) << 16);
                floatx4 p0 = { __uint_as_float(dw[0]), __uint_as_float(dw[1]),
                               __uint_as_float(dw[2]), __uint_as_float(dw[3]) };
                floatx4 p1 = { __uint_as_float(dw[4]), __uint_as_float(dw[5]),
                               __uint_as_float(dw[6]), __uint_as_float(dw[7]) };
                char* dstp = (char*)STg + ((size_t)(b*256 + l)*256 + d0)*2;
                stc4((float*)dstp, p0);
                stc4((float*)(dstp + 16), p1);
                if (tid == 0)
                    stc(&normp[b*16 + rem], wsum[0] + wsum[1] + wsum[2] + wsum[3]);
            }
            if (t == Ln - 1) {
#pragma unroll
                for (int cq = 0; cq < 4; ++cq)
                    *(floatx4*)&outS[(size_t)(b*256 + d0 + r)*256 + m*4 + 64*cq] = S_reg[cq];
            }
        }
        grid_sync_b(bflags, rem, ++kbar);

        // ======================= PHASE C =======================
        {
            // c1: ONE batched MALL round trip (ST panel + u + a + norm)
            {
                int lq = tid >> 2, kq = (tid & 3) * 64;
                const char* src = (const char*)STg + ((size_t)(b*256 + l0 + lq)*256 + kq)*2;
                const float* pu = &u_buf[(size_t)b*2048 + tid*8];
                const float* pa = &a_buf[(size_t)b*2048 + tid*8];
                const float* pn = (tid < 16) ? &normp[b*16 + tid] : pu;
                floatx4 r0,r1,r2,r3,r4,r5,r6,r7,u0,u1,a0,a1; float nsc;
                ldc4x12s(r0,r1,r2,r3,r4,r5,r6,r7,u0,u1,a0,a1,nsc,
                    (const float*)(src+0),  (const float*)(src+16),
                    (const float*)(src+32), (const float*)(src+48),
                    (const float*)(src+64), (const float*)(src+80),
                    (const float*)(src+96), (const float*)(src+112),
                    pu, pu+4, pa, pa+4, pn);
                size_t rb0 = (size_t)lq*528 + (size_t)kq*2;
                unsigned swz = (unsigned)((lq & 8) << 1);
                *(floatx4*)(STb + ((rb0 +   0) ^ swz)) = r0;
                *(floatx4*)(STb + ((rb0 +  16) ^ swz)) = r1;
                *(floatx4*)(STb + ((rb0 +  32) ^ swz)) = r2;
                *(floatx4*)(STb + ((rb0 +  48) ^ swz)) = r3;
                *(floatx4*)(STb + ((rb0 +  64) ^ swz)) = r4;
                *(floatx4*)(STb + ((rb0 +  80) ^ swz)) = r5;
                *(floatx4*)(STb + ((rb0 +  96) ^ swz)) = r6;
                *(floatx4*)(STb + ((rb0 + 112) ^ swz)) = r7;
                *(floatx4*)&uvp[tid*8]     = u0; *(floatx4*)&uvp[tid*8 + 4] = u1;
                *(floatx4*)&avp[tid*8]     = a0; *(floatx4*)&avp[tid*8 + 4] = a1;
                if (tid < 16) nrml[tid] = nsc;
                if (tid < 64) {
                    *(floatx4*)&thv[tid*4] = *(const floatx4*)&thetaB[(size_t)(b*Ln + t)*Dn + tid*4];
                    *(floatx4*)&kT[tid*4]  = *(const floatx4*)&kphi[(size_t)(b*Ln + t)*Dn + tid*4];
                }
                if (tid < 16)
                    *(floatx4*)&Kl[tid*4] = *(const floatx4*)&Kall[(size_t)(b*Ln + t)*64 + tid*4];
                if (t < Ln - 1) {
#pragma unroll
                    for (int q = 0; q < 2; ++q) {
                        int w = q*4 + (tid >> 6);
                        int c4 = (tid & 63) << 2;
                        int tk = t + 1 - 7 + w;
                        floatx4 kv = {0.f,0.f,0.f,0.f};
                        if (tk >= 0) kv = *(const floatx4*)&kphi[(size_t)(b*Ln + tk)*Dn + c4];
                        *(floatx4*)&kW2[w*256 + c4] = kv;
                    }
                }
            }
            __syncthreads();

            // c2: c = a + 0.5 G u
#pragma unroll
            for (int q = 0; q < 8; ++q) {
                int idx = q*256 + tid;
                int w = idx >> 8, e = idx & 255;
                float sv = avp[idx];
#pragma unroll
                for (int w2 = 0; w2 < 8; ++w2)
                    sv += 0.5f * Kl[w*8 + w2] * uvp[w2*256 + e];
                cvp[idx] = sv;
            }
            __syncthreads();

            // c3: T update IN REGISTERS (A-frag layout): T = thth*T + uc^T + cu^T
            {
                int i = i0 + wid*16 + lme;
                float thi = thv[i];
                float ui8[8], ci8[8];
#pragma unroll
                for (int w = 0; w < 8; ++w) { ui8[w] = uvp[w*256 + i]; ci8[w] = cvp[w*256 + i]; }
#pragma unroll
                for (int kc = 0; kc < 8; ++kc) {
                    int k0 = kc*32 + hi*8;
                    floatx4 th0 = *(const floatx4*)&thv[k0];
                    floatx4 th1 = *(const floatx4*)&thv[k0 + 4];
                    floatx4 t0 = (thi * th0) * T_reg[kc*2+0];
                    floatx4 t1 = (thi * th1) * T_reg[kc*2+1];
#pragma unroll
                    for (int w = 0; w < 8; ++w) {
                        floatx4 uk0 = *(const floatx4*)&uvp[w*256 + k0];
                        floatx4 uk1 = *(const floatx4*)&uvp[w*256 + k0 + 4];
                        floatx4 ck0 = *(const floatx4*)&cvp[w*256 + k0];
                        floatx4 ck1 = *(const floatx4*)&cvp[w*256 + k0 + 4];
                        t0 += ui8[w]*ck0 + ci8[w]*uk0;
                        t1 += ui8[w]*ck1 + ci8[w]*uk1;
                    }
                    T_reg[kc*2+0] = t0;
                    T_reg[kc*2+1] = t1;
                }
            }

            // c5: MFMA TS tile (A = T regs -> bf16; B = swizzled S^T bf16 LDS)
            floatx4 acc[4];
#pragma unroll
            for (int lt = 0; lt < 4; ++lt) acc[lt] = (floatx4){0.f,0.f,0.f,0.f};
#pragma unroll
            for (int kc = 0; kc < 8; ++kc) {
                BF8 ua; ua.u[0] = packbf4(T_reg[kc*2]); ua.u[1] = packbf4(T_reg[kc*2+1]);
                int kbyte = kc*64 + hi*16;
#pragma unroll
                for (int lt = 0; lt < 4; ++lt) {
                    int row = lt*16 + lme;
                    short8 bf = *(const short8*)(STb +
                        (((size_t)row*528 + kbyte) ^ (unsigned)((row & 8) << 1)));
                    acc[lt] = __builtin_amdgcn_mfma_f32_16x16x32_bf16(ua.s8, bf, acc[lt], 0,0,0);
                }
            }

            // c6: NS, M update, y partial (slot store)
            {
                float nsq = 0.f;
#pragma unroll
                for (int q = 0; q < 16; ++q) nsq += nrml[q];
                float nrm = sqrtf(nsq) + 1e-7f;
                float inv_n = 1.f / nrm;
                float w1 = 1.5f * inv_n;
                float w3 = 0.5f * inv_n * inv_n * inv_n;
                float alv[4], etv[4], kvr[4];
#pragma unroll
                for (int g = 0; g < 4; ++g) {
                    alv[g] = alphaB[(size_t)(b*Ln + t)*Dn + ibr + g];
                    etv[g] = etaB[(size_t)(b*Ln + t)*Dn + ibr + g];
                }
#pragma unroll
                for (int lt = 0; lt < 4; ++lt) kvr[lt] = kT[l0 + lt*16 + lme];
                float py[4] = {0.f,0.f,0.f,0.f};
#pragma unroll
                for (int lt = 0; lt < 4; ++lt)
#pragma unroll
                    for (int g = 0; g < 4; ++g) {
                        int l_loc = lt*16 + lme;
                        unsigned short sb = *(const unsigned short*)(STb +
                            (((size_t)l_loc*528 + (size_t)(ibr + g)*2) ^ (unsigned)((l_loc & 8) << 1)));
                        float s_il = __uint_as_float(((unsigned)sb) << 16);
                        float ns = w1 * s_il - w3 * acc[lt][g];
                        float mn = alv[g] * M_reg[lt*4+g] - etv[g] * ns;
                        M_reg[lt*4+g] = mn;
                        py[g] += mn * kvr[lt];
                        if (t == Ln - 1)
                            outM[(size_t)(b*256 + ibr + g)*256 + l0 + l_loc] = mn;
                    }
#pragma unroll
                for (int g = 0; g < 4; ++g) {
                    py[g] += __shfl_xor(py[g], 1); py[g] += __shfl_xor(py[g], 2);
                    py[g] += __shfl_xor(py[g], 4); py[g] += __shfl_xor(py[g], 8);
                    if (lme == 0)
                        stc(&ysp[(size_t)s*BLD + (size_t)(b*Ln + t)*Dn + ibr + g], py[g]);
                }
            }

            // c7: next-step err partials -> slot stores, parity (t+1)&1
            if (t < Ln - 1) {
                const int p2 = (t + 1) & 1;
#pragma unroll
                for (int w = 0; w < 8; ++w) {
                    float pd[4] = {0.f,0.f,0.f,0.f};
#pragma unroll
                    for (int lt = 0; lt < 4; ++lt) {
                        float kv2 = kW2[w*256 + l0 + lt*16 + lme];
#pragma unroll
                        for (int g = 0; g < 4; ++g) pd[g] += M_reg[lt*4+g] * kv2;
                    }
#pragma unroll
                    for (int g = 0; g < 4; ++g) {
                        pd[g] += __shfl_xor(pd[g], 1); pd[g] += __shfl_xor(pd[g], 2);
                        pd[g] += __shfl_xor(pd[g], 4); pd[g] += __shfl_xor(pd[g], 8);
                    }
                    if (lme == 0)
#pragma unroll
                        for (int g = 0; g < 4; ++g)
                            stc(&errp_g[(size_t)((s*2 + p2)*4 + b)*2048 + w*256 + ibr + g], pd[g]);
                }
            }
        }
        grid_sync_b(bflags, rem, ++kbar);
    }
}

// -------------------------------------------------------------------------
extern "C" void kernel_launch(void* const* d_in, const int* in_sizes, int n_in,
                              void* d_out, int out_size, void* d_ws, size_t ws_size,
                              hipStream_t stream)
{
    const float* x       = (const float*)d_in[0];
    const float* k_al    = (const float*)d_in[1];
    const float* v       = (const float*)d_in[2];
    const float* M_prev  = (const float*)d_in[3];
    const float* S_prev  = (const float*)d_in[4];
    const float* poly    = (const float*)d_in[5];
    const float* alpha_W = (const float*)d_in[6];
    const float* alpha_b = (const float*)d_in[7];
    const float* eta_W   = (const float*)d_in[8];
    const float* eta_b   = (const float*)d_in[9];
    const float* theta_W = (const float*)d_in[10];
    const float* theta_b = (const float*)d_in[11];
    const float* gamma_W = (const float*)d_in[12];
    const float* gamma_b = (const float*)d_in[13];
    const float* out_W   = (const float*)d_in[14];
    const float* out_b   = (const float*)d_in[15];

    float* ws = (float*)d_ws;
    float* kphi    = ws;                    // 262144
    float* alphaB  = kphi   + BLD;          // 262144
    float* etaB    = alphaB + BLD;          // 262144
    float* thetaB  = etaB   + BLD;          // 262144
    float* gammaB  = thetaB + BLD;          // 1024
    float* Kall    = gammaB + Bn*Ln;        // 65536
    float* STg_f   = Kall   + Bn*Ln*64;     // 131072 (bf16 [B][256][256])
    float* u_bufp  = STg_f  + 131072;       // 8192
    float* a_bufp  = u_bufp + Bn*Wn*Dn;     // 8192
    float* errp    = a_bufp + Bn*Wn*Dn;     // 65536 (4 slots x 2 par x B x 8 x 256)
    float* normp   = errp   + 65536;        // 64
    float* ysp     = normp  + 64;           // 4 x 262144
    unsigned* flags = (unsigned*)(ysp + 4*BLD);  // 2048 u32

    float* out_y = (float*)d_out;           // [B,L,D]
    float* outM  = out_y + BLD;             // [B,D,D]
    float* outS  = outM + BDD;              // [B,D,D]

    // precompute
    hipLaunchKernelGGL(kphi_gamma_kernel, dim3(256), dim3(256), 0, stream,
                       k_al, x, poly, gamma_W, gamma_b, kphi, gammaB);
    hipLaunchKernelGGL((gemm_act_kernel<1>), dim3(32, 4), dim3(256), 0, stream,
                       x, alpha_W, alpha_b, alphaB);
    hipLaunchKernelGGL((gemm_act_kernel<2>), dim3(32, 4), dim3(256), 0, stream,
                       x, eta_W, eta_b, etaB);
    hipLaunchKernelGGL((gemm_act_kernel<1>), dim3(32, 4), dim3(256), 0, stream,
                       x, theta_W, theta_b, thetaB);
    hipLaunchKernelGGL(kgram_kernel, dim3(Ln, Bn), dim3(64), 0, stream,
                       kphi, Kall);
    hipLaunchKernelGGL(prologue_kernel, dim3(2), dim3(256), 0, stream, flags);

    // persistent scan
    hipLaunchKernelGGL(scan_kernel, dim3(NBLK), dim3(256), 0, stream,
                       kphi, v, gammaB, alphaB, etaB, thetaB, Kall,
                       M_prev, S_prev, (unsigned short*)STg_f,
                       u_bufp, a_bufp, errp, normp, ysp, flags,
                       outM, outS);

    // fold y slots, then out projection
    hipLaunchKernelGGL(ysum_kernel, dim3(256), dim3(256), 0, stream, ysp);
    hipLaunchKernelGGL((gemm_act_kernel<0>), dim3(32, 4), dim3(256), 0, stream,
                       ysp, out_W, out_b, out_y);
}